// Round 5
// baseline (353.871 us; speedup 1.0000x reference)
//
#include <hip/hip_runtime.h>

#define NB 128
#define T_DIM 50
#define Q_DIM 1024
#define H_DIM 256
#define S_DIM 49                 // MAX_STEP - 1
#define K_DIM 51200              // T*Q
#define KCHUNKS 80
#define KC 640                   // K per chunk
#define BK 64                    // K per LDS stage
#define NSTAGE 10                // KC/BK
#define GRAM_N (NB * NB)         // 16384
#define LROWU 36                 // uints per padded LDS row (64 f16 + 8 pad)
#define CPAD 132                 // padded f32 row for sinkhorn cost matrix

typedef __attribute__((ext_vector_type(4))) float f32x4;
typedef __attribute__((ext_vector_type(8))) _Float16 half8v;
typedef __attribute__((ext_vector_type(4))) unsigned int uint4v;
typedef __attribute__((ext_vector_type(2))) unsigned int uint2v;
using pk2_t = decltype(__builtin_amdgcn_cvt_pkrtz(0.0f, 0.0f));

union PKU { pk2_t p; unsigned int u; };
union U4H8 { uint4v u; half8v h; };

__device__ inline unsigned short f2bf_rn(float x) {   // round-nearest-even bf16
  union { float f; unsigned int u; } v; v.f = x;
  unsigned int r = v.u + 0x7FFFu + ((v.u >> 16) & 1u);
  return (unsigned short)(r >> 16);
}
__device__ inline float bf2f(unsigned short b) {
  union { float f; unsigned int u; } v; v.u = ((unsigned int)b) << 16;
  return v.f;
}

// ---------------------------------------------------------------------------
// gram_fused helpers (512-thread half-block version)
// Staging map: r0 = tid>>2 (0..127), q = tid&3. Thread loads 4 f32x4 per
// matrix at float offsets q*4 + j*16 (j=0..3): per instruction, lanes q=0..3
// cover 64B contiguous -> fully coalesced (same pattern as the verified
// round-0 kernel). cvt_write packs each f32x4 -> uint2v at uint offset
// q*2 + j*8 of the padded 36-uint LDS row.
// ---------------------------------------------------------------------------
__device__ __forceinline__ void issue_loads2(
    const float* __restrict__ S, const float* __restrict__ Tm,
    size_t ro, int kpos,
    f32x4 (&pS)[4], f32x4 (&pT)[4]) {
#pragma unroll
  for (int j = 0; j < 4; j++) {
    pS[j] = *(const f32x4*)(S + ro + kpos + j * 16);
    pT[j] = *(const f32x4*)(Tm + ro + kpos + j * 16);
  }
}

__device__ __forceinline__ void cvt_write2(
    unsigned int* __restrict__ panA, unsigned int* __restrict__ panB,
    int r0, int q,
    const f32x4 (&pS)[4], const f32x4 (&pT)[4]) {
#pragma unroll
  for (int j = 0; j < 4; j++) {
    PKU a, b; uint2v w;
    a.p = __builtin_amdgcn_cvt_pkrtz(pS[j][0], pS[j][1]);
    b.p = __builtin_amdgcn_cvt_pkrtz(pS[j][2], pS[j][3]);
    w.x = a.u; w.y = b.u;
    *(uint2v*)&panA[r0 * LROWU + q * 2 + j * 8] = w;
    a.p = __builtin_amdgcn_cvt_pkrtz(pT[j][0], pT[j][1]);
    b.p = __builtin_amdgcn_cvt_pkrtz(pT[j][2], pT[j][3]);
    w.x = a.u; w.y = b.u;
    *(uint2v*)&panB[r0 * LROWU + q * 2 + j * 8] = w;
  }
}

__device__ __forceinline__ void compute_stage2(
    const unsigned int* __restrict__ panA, const unsigned int* __restrict__ panB,
    int rowbase, int wcol, int l15, int quad,
    f32x4 (&aXY)[2][2], f32x4 (&aXX)[2][2], f32x4 (&aYY)[2][2]) {
#pragma unroll
  for (int ks = 0; ks < 2; ks++) {
    const int kc = ks * 16 + quad * 4;
    half8v as_[2], bs_[2], at_[2], bt_[2];
#pragma unroll
    for (int t = 0; t < 2; t++) {
      U4H8 u;
      u.u = *(const uint4v*)&panA[(rowbase + t * 16 + l15) * LROWU + kc];   as_[t] = u.h;
      u.u = *(const uint4v*)&panA[(wcol * 32 + t * 16 + l15) * LROWU + kc]; bs_[t] = u.h;
      u.u = *(const uint4v*)&panB[(rowbase + t * 16 + l15) * LROWU + kc];   at_[t] = u.h;
      u.u = *(const uint4v*)&panB[(wcol * 32 + t * 16 + l15) * LROWU + kc]; bt_[t] = u.h;
    }
#pragma unroll
    for (int ti = 0; ti < 2; ti++)
#pragma unroll
      for (int tj = 0; tj < 2; tj++) {
        aXY[ti][tj] = __builtin_amdgcn_mfma_f32_16x16x32_f16(as_[ti], bt_[tj], aXY[ti][tj], 0, 0, 0);
        aXX[ti][tj] = __builtin_amdgcn_mfma_f32_16x16x32_f16(as_[ti], bs_[tj], aXX[ti][tj], 0, 0, 0);
        aYY[ti][tj] = __builtin_amdgcn_mfma_f32_16x16x32_f16(at_[ti], bt_[tj], aYY[ti][tj], 0, 0, 0);
      }
  }
}

// ---------------------------------------------------------------------------
// Kernel 1: FUSED per-pair grams via 16x16x32 f16 MFMA — HALF-BLOCK design.
// grid = (KCHUNKS, 2 halves, 3 pairs) = 480 blocks, block = 512 (8 waves).
//
// Round-5: the single-16-wave-block design plateaued at 66-70us across 3
// schedule variants (MfmaUtil ~8%, occupancy 33%): ONE barrier domain per CU
// means every stage's ~12k cy of exposed latency idles the whole CU, and the
// compiler sinks deep prefetch when the 16-wave register budget is tight.
// Fix: split each tile into 2 independent 8-wave half-blocks (rows [h*64,
// h*64+64) x 128 cols x 3 kinds). LDS per block unchanged (73728 B) ->
// 2 blocks/CU co-resident (147456 <= 163840), 480 blocks = ALL resident;
// one block's barrier stall overlaps the other's compute/loads. Per-lane
// state ~150 regs fits the 4-waves/SIMD budget (512) - no spill risk.
// Staging traffic doubles (both halves load full panels) but same-chunk
// halves run concurrently -> L2/L3 absorb the duplicate.
// Partial layout + reduce kernel UNCHANGED (halves write disjoint rows).
// Numerics identical to round 0 (same RTZ cvt, MFMA, chunking, bf16 parts).
// Schedule = round-3 proven 1-barrier dbuf:
//   prologue: issue(0); write L0; barrier
//   iter st:  issue(st+1); compute L[st&1]; write L[(st+1)&1]; barrier
// ---------------------------------------------------------------------------
__global__ __launch_bounds__(512) void gram_fused_kernel(
    const float* __restrict__ s0, const float* __restrict__ s1, const float* __restrict__ s2,
    const float* __restrict__ t0, const float* __restrict__ t1, const float* __restrict__ t2,
    unsigned short* __restrict__ part) {
  __shared__ unsigned int pan[2][2][NB * LROWU];   // [buf][A/B], 73728 B

  const int chunk = blockIdx.x;
  const int hblk = blockIdx.y;                     // 0/1: row half
  const int pair = blockIdx.z;
  const float* S  = (pair == 0) ? s0 : ((pair == 1) ? s1 : s2);
  const float* Tm = (pair == 0) ? t0 : ((pair == 1) ? t1 : t2);

  const int tid = threadIdx.x;                     // 0..511
  const int wave = tid >> 6, lane = tid & 63;
  const int wrow = wave >> 2;                      // 0..1
  const int wcol = wave & 3;                       // 0..3
  const int l15 = lane & 15, quad = lane >> 4;
  const int rowbase = hblk * 64 + wrow * 32;       // A-side row base

  f32x4 aXY[2][2], aXX[2][2], aYY[2][2];
#pragma unroll
  for (int i = 0; i < 2; i++)
#pragma unroll
    for (int j = 0; j < 2; j++) {
      aXY[i][j] = (f32x4){0.f, 0.f, 0.f, 0.f};
      aXX[i][j] = (f32x4){0.f, 0.f, 0.f, 0.f};
      aYY[i][j] = (f32x4){0.f, 0.f, 0.f, 0.f};
    }

  const int r0 = tid >> 2;               // 0..127 staging row
  const int q  = tid & 3;                // 0..3
  const size_t ro = (size_t)r0 * K_DIM + q * 4;
  const int kbase = chunk * KC;

  f32x4 pS[4], pT[4];

  issue_loads2(S, Tm, ro, kbase, pS, pT);
  cvt_write2(&pan[0][0][0], &pan[0][1][0], r0, q, pS, pT);
  __syncthreads();

  for (int st = 0; st < NSTAGE; st++) {
    const int buf = st & 1;
    if (st + 1 < NSTAGE) issue_loads2(S, Tm, ro, kbase + (st + 1) * BK, pS, pT);
    compute_stage2(&pan[buf][0][0], &pan[buf][1][0], rowbase, wcol, l15, quad, aXY, aXX, aYY);
    if (st + 1 < NSTAGE) {
      cvt_write2(&pan[buf ^ 1][0][0], &pan[buf ^ 1][1][0], r0, q, pS, pT);
      __syncthreads();
    }
  }

#pragma unroll
  for (int kind = 0; kind < 3; kind++) {
    unsigned short* out = part + ((size_t)(pair * 3 + kind) * KCHUNKS + chunk) * GRAM_N;
#pragma unroll
    for (int ti = 0; ti < 2; ti++)
#pragma unroll
      for (int tj = 0; tj < 2; tj++) {
        const f32x4 v = (kind == 0) ? aXY[ti][tj] : ((kind == 1) ? aXX[ti][tj] : aYY[ti][tj]);
        const int col = wcol * 32 + tj * 16 + l15;
#pragma unroll
        for (int r = 0; r < 4; r++) {
          const int row = rowbase + ti * 16 + quad * 4 + r;
          out[(size_t)row * NB + col] = f2bf_rn(v[r]);
        }
      }
  }
}

// ---------------------------------------------------------------------------
// Kernel 2: reduce bf16 K-chunk partials -> gram[9][128][128] (f32)
// ---------------------------------------------------------------------------
__global__ __launch_bounds__(256) void gram_reduce_kernel(
    const unsigned short* __restrict__ part, float* __restrict__ gram) {
  const int idx = blockIdx.x * 256 + threadIdx.x;   // < 9*16384
  const int g = idx >> 14;
  const int cell = idx & (GRAM_N - 1);
  const unsigned short* p = part + (size_t)g * KCHUNKS * GRAM_N + cell;
  float s = 0.f;
#pragma unroll
  for (int c = 0; c < KCHUNKS; c++) s += bf2f(p[(size_t)c * GRAM_N]);
  gram[idx] = s;
}

// ---------------------------------------------------------------------------
// Kernel 3: Sinkhorn, per (pair, kind) chain. (unchanged — verified 4x)
// ---------------------------------------------------------------------------
__global__ __launch_bounds__(256, 1) void sinkhorn_part_kernel(
    const float* __restrict__ gram, float* __restrict__ kdpart) {
  const int pair = blockIdx.x, kind = blockIdx.y;
  const float* Gxy = gram + (size_t)(3 * pair + 0) * GRAM_N;
  const float* Gxx = gram + (size_t)(3 * pair + 1) * GRAM_N;
  const float* Gyy = gram + (size_t)(3 * pair + 2) * GRAM_N;

  __shared__ float CL[NB * CPAD];     // 67584 B, f32 cost matrix
  __shared__ f32x4 h4a[NB / 4];       // pot0 (f-side)
  __shared__ f32x4 h4b[NB / 4];       // pot1 (g-side, kind0 only)
  __shared__ float nx[NB], ny[NB];
  __shared__ float red[256];

  const int tid = threadIdx.x;
  if (tid < NB) {
    nx[tid] = Gxx[tid * (NB + 1)];
    ny[tid] = Gyy[tid * (NB + 1)];
    ((float*)h4a)[tid] = 0.f;
    ((float*)h4b)[tid] = 0.f;
  }
  __syncthreads();

  const float* G  = (kind == 0) ? Gxy : ((kind == 1) ? Gxx : Gyy);
  const float* rn = (kind == 2) ? ny : nx;
  const float* cn = (kind == 1) ? nx : ny;
  for (int idx = tid; idx < GRAM_N; idx += 256) {
    const int i = idx >> 7, j = idx & 127;
    CL[i * CPAD + j] = 2.0f * fmaxf(rn[i] + cn[j] - 2.0f * G[idx], 0.0f);
  }
  __syncthreads();

  const float rho = 250000.0f;
  const float AL = -4.852030263919617f;     // -log(128)
  const float LOG2E = 1.4426950408889634f;
  const float LN2 = 0.6931471805599453f;
  const int grp = tid >> 7;
  const int i = tid & 127;
  const bool active = (kind == 0) || (grp == 0);
  const bool colread = (kind == 0) && (grp == 1);

  // register-cache this thread's C row (or column for gt)
  f32x4 crow[32];
  if (active) {
    if (colread) {
#pragma unroll
      for (int jj = 0; jj < 32; jj++) {
        f32x4 v;
        v[0] = CL[(4 * jj + 0) * CPAD + i];
        v[1] = CL[(4 * jj + 1) * CPAD + i];
        v[2] = CL[(4 * jj + 2) * CPAD + i];
        v[3] = CL[(4 * jj + 3) * CPAD + i];
        crow[jj] = v;
      }
    } else {
#pragma unroll
      for (int jj = 0; jj < 32; jj++)
        crow[jj] = *(const f32x4*)&CL[i * CPAD + 4 * jj];
    }
  }

  float eps = 1.0f;
  for (int it = 0; it < 9; it++) {
    if (it == 8) eps = 2.5e-5f;             // BLUR^P
    const float inv_eps = 1.0f / eps;
    const float damp = 1.0f / (1.0f + eps / rho);
    const float ebl = eps * AL;

    float newp = 0.f;
    if (active) {
      const f32x4* h = (kind == 0 && grp == 0) ? h4b : h4a;
      // pass 1: m = max_j (h[j] - C[j])
      f32x4 m4 = (f32x4){-3.0e38f, -3.0e38f, -3.0e38f, -3.0e38f};
#pragma unroll
      for (int jj = 0; jj < 32; jj++) {
        const f32x4 u = h[jj] - crow[jj];
        m4[0] = fmaxf(m4[0], u[0]); m4[1] = fmaxf(m4[1], u[1]);
        m4[2] = fmaxf(m4[2], u[2]); m4[3] = fmaxf(m4[3], u[3]);
      }
      const float m = fmaxf(fmaxf(m4[0], m4[1]), fmaxf(m4[2], m4[3]));
      // pass 2: S = sum_j exp2((u - m) * k); subtract-first keeps arg <= 0
      const float k = inv_eps * LOG2E;
      f32x4 s4 = (f32x4){0.f, 0.f, 0.f, 0.f};
#pragma unroll
      for (int jj = 0; jj < 32; jj++) {
        const f32x4 u = h[jj] - crow[jj];
        s4[0] += __builtin_exp2f((u[0] - m) * k);
        s4[1] += __builtin_exp2f((u[1] - m) * k);
        s4[2] += __builtin_exp2f((u[2] - m) * k);
        s4[3] += __builtin_exp2f((u[3] - m) * k);
      }
      const float Ssum = (s4[0] + s4[1]) + (s4[2] + s4[3]);   // >= 1
      // softmin = -(m + ebl + eps*ln(S))
      const float sm = -(m + ebl + eps * (LN2 * __log2f(Ssum)));
      if (kind == 0) newp = damp * sm;
      else           newp = 0.5f * (((const float*)h4a)[i] + damp * sm);
    }
    __syncthreads();                        // all reads of h done
    if (active) {
      if (grp == 0) ((float*)h4a)[i] = newp;
      else          ((float*)h4b)[i] = newp;
    }
    __syncthreads();                        // new pots visible
    eps *= 0.25f;                           // SCALING^P
  }

  float v = 0.f;
  if (kind == 0) {
    v = (grp == 0) ? -__expf(-((const float*)h4a)[i] / rho)
                   : -__expf(-((const float*)h4b)[i] / rho);
  } else if (grp == 0) {
    v = __expf(-((const float*)h4a)[i] / rho);
  }
  red[tid] = v;
  __syncthreads();
  for (int st = 128; st > 0; st >>= 1) {
    if (tid < st) red[tid] += red[tid + st];
    __syncthreads();
  }
  if (tid == 0) kdpart[pair * 3 + kind] = red[0];
}

// ---------------------------------------------------------------------------
// Kernel 4: one-hot gather. ONE WAVE per (b,s) — ballot+shfl, no LDS/barrier.
// ---------------------------------------------------------------------------
__global__ __launch_bounds__(256) void ps_kernel(
    const float* __restrict__ lc, const float* __restrict__ lt, const float* __restrict__ le,
    const float* __restrict__ batch,
    float* __restrict__ pc, float* __restrict__ pt, float* __restrict__ pe,
    float* __restrict__ aarr) {
  const int w = blockIdx.x * 4 + (threadIdx.x >> 6);   // wave id = b*S_DIM+s
  if (w >= NB * S_DIM) return;
  const int lane = threadIdx.x & 63;
  const int b = w / S_DIM, s = w - b * S_DIM;
  const float* brow = batch + ((size_t)b * T_DIM + (s + 1)) * (2 * Q_DIM);

  int qv = 0; float dsv = 0.f; bool found = false;
#pragma unroll
  for (int c = 0; c < 4; c++) {
    const int base = c * 256 + lane * 4;             // coalesced f32x4
    const f32x4 d0 = *(const f32x4*)(brow + base);
    const f32x4 d1 = *(const f32x4*)(brow + Q_DIM + base);
#pragma unroll
    for (int j = 0; j < 4; j++)
      if (d0[j] + d1[j] > 0.5f) { qv = base + j; dsv = d0[j] - d1[j]; found = true; }
  }
  const unsigned long long m = __ballot(found);
  const int src = (m != 0ull) ? (__ffsll((unsigned long long)m) - 1) : 0;
  qv = __shfl(qv, src, 64);
  dsv = __shfl(dsv, src, 64);
  if (lane == 0) {
    const size_t off = ((size_t)b * T_DIM + s) * Q_DIM + qv;
    pc[w] = 2.0f * lc[off];   // 1/TEMP
    pt[w] = 2.0f * lt[off];
    pe[w] = 2.0f * le[off];
    aarr[w] = (m != 0ull && dsv > 0.0f) ? 1.0f : 0.0f;
  }
}

// ---------------------------------------------------------------------------
// Kernel 5: embed loss: sum of squared diffs. 1600 blocks = 1 tile/thread.
// ---------------------------------------------------------------------------
__global__ __launch_bounds__(256) void embed_kernel(
    const f32x4* __restrict__ hs, const f32x4* __restrict__ ht,
    const f32x4* __restrict__ ds, const f32x4* __restrict__ dt,
    float* __restrict__ acc) {
  const int N4 = NB * T_DIM * H_DIM / 4;   // 409600
  float sum = 0.f;
  for (int idx = blockIdx.x * 256 + threadIdx.x; idx < N4; idx += gridDim.x * 256) {
    f32x4 a = hs[idx] - ht[idx];
    f32x4 b = ds[idx] - dt[idx];
    sum += a[0]*a[0] + a[1]*a[1] + a[2]*a[2] + a[3]*a[3]
         + b[0]*b[0] + b[1]*b[1] + b[2]*b[2] + b[3]*b[3];
  }
  for (int off = 32; off > 0; off >>= 1) sum += __shfl_down(sum, off, 64);
  __shared__ float wsum[4];
  const int lane = threadIdx.x & 63, wv = threadIdx.x >> 6;
  if (lane == 0) wsum[wv] = sum;
  __syncthreads();
  if (threadIdx.x == 0) atomicAdd(acc, wsum[0] + wsum[1] + wsum[2] + wsum[3]);
}

// ---------------------------------------------------------------------------
// Kernel 6: masked CE + final combine. 1 block, 128 threads. LDS-staged.
// ---------------------------------------------------------------------------
__global__ __launch_bounds__(128) void ce_final_kernel(
    const float* __restrict__ pc, const float* __restrict__ pt, const float* __restrict__ pe,
    const float* __restrict__ aarr, const float* __restrict__ kdpart,
    const float* __restrict__ emb, float* __restrict__ out) {
  __shared__ float sx[4][NB][S_DIM];   // 0:pt 1:pc 2:pe 3:a — 100352 B
  const int tid = threadIdx.x;
  for (int idx = tid; idx < NB * S_DIM; idx += 128) {
    const int b = idx / S_DIM, s = idx - b * S_DIM;
    sx[0][b][s] = pt[idx];
    sx[1][b][s] = pc[idx];
    sx[2][b][s] = pe[idx];
    sx[3][b][s] = aarr[idx];
  }
  __syncthreads();

  const int b = tid;
  int last = -1;
  for (int s = 0; s < S_DIM; s++)
    if (sx[1][b][s] > 0.0f) last = s;
  const int L = (last >= 0) ? (last + 1) : S_DIM;

  float loss = 0.f;
#pragma unroll
  for (int k = 0; k < 3; k++) {
    float m = -3.0e38f;
    for (int s = 0; s < L; s++) m = fmaxf(m, sx[k][b][s]);
    float sum = 0.f;
    for (int s = 0; s < L; s++) sum += __expf(sx[k][b][s] - m);
    const float lse = m + __logf(sum);
    float l = 0.f;
    for (int s = 0; s < L; s++) l += sx[3][b][s] * (sx[k][b][s] - lse);
    loss -= l;
  }

  __shared__ float red[128];
  red[b] = loss;
  __syncthreads();
  for (int st = 64; st > 0; st >>= 1) {
    if (b < st) red[b] += red[b + st];
    __syncthreads();
  }
  if (b == 0) {
    float kd = 0.f;
    for (int k = 0; k < 9; k++) kd += kdpart[k];
    // w * a_w = (rho + eps_final/2) / 128 ; DIST_W = 0.01
    out[0] = red[0] + 0.01f * (250000.0000125f / 128.0f) * kd + 0.5f * emb[0];
  }
}

// ---------------------------------------------------------------------------
extern "C" void kernel_launch(void* const* d_in, const int* in_sizes, int n_in,
                              void* d_out, int out_size, void* d_ws, size_t ws_size,
                              hipStream_t stream) {
  const float* lc    = (const float*)d_in[0];
  const float* lt    = (const float*)d_in[1];
  const float* le    = (const float*)d_in[2];
  const float* ltc   = (const float*)d_in[3];
  const float* ltt   = (const float*)d_in[4];
  const float* lte   = (const float*)d_in[5];
  const float* ohs   = (const float*)d_in[6];
  const float* oht   = (const float*)d_in[7];
  const float* ods   = (const float*)d_in[8];
  const float* odt   = (const float*)d_in[9];
  const float* batch = (const float*)d_in[10];

  unsigned short* part = (unsigned short*)d_ws;        // 9*80*16384*2B = 23.6 MB
  float* gram = (float*)(part + (size_t)9 * KCHUNKS * GRAM_N);  // 9*16384 f32
  float* pcb  = gram + 9 * GRAM_N;                     // 128*49 each
  float* ptb  = pcb + NB * S_DIM;
  float* peb  = ptb + NB * S_DIM;
  float* ab   = peb + NB * S_DIM;
  float* kdp  = ab + NB * S_DIM;                       // 9
  float* emb  = kdp + 9;                               // 1

  hipMemsetAsync(emb, 0, sizeof(float), stream);

  embed_kernel<<<1600, 256, 0, stream>>>(
      (const f32x4*)ohs, (const f32x4*)oht, (const f32x4*)ods, (const f32x4*)odt, emb);

  ps_kernel<<<(NB * S_DIM + 3) / 4, 256, 0, stream>>>(lc, lt, le, batch, pcb, ptb, peb, ab);

  gram_fused_kernel<<<dim3(KCHUNKS, 2, 3), 512, 0, stream>>>(lc, lt, le, ltc, ltt, lte, part);

  gram_reduce_kernel<<<(9 * GRAM_N) / 256, 256, 0, stream>>>(part, gram);

  sinkhorn_part_kernel<<<dim3(3, 3), 256, 0, stream>>>(gram, kdp);

  ce_final_kernel<<<1, 128, 0, stream>>>(pcb, ptb, peb, ab, kdp, emb, (float*)d_out);
}